// Round 18
// baseline (208.684 us; speedup 1.0000x reference)
//
#include <hip/hip_runtime.h>

#define HS 1024
#define NH 16
#define PS 64
#define SS 2048
#define NB 4
#define MTOT (NB * SS)
// 0.125 (1/sqrt(64)) * log2(e): scores land in log2-domain for v_exp_f32 (2^x)
#define QSCALE 0.18033688011112042f

typedef __bf16 bf16x8 __attribute__((ext_vector_type(8)));
typedef float f32x4 __attribute__((ext_vector_type(4)));

__device__ __forceinline__ unsigned short f2bf(float f) {
  union { __bf16 h; unsigned short u; } c;
  c.h = (__bf16)f;
  return c.u;
}
__device__ __forceinline__ unsigned int pk2(float a, float b) {
  union { __bf16 h[2]; unsigned int u; } c;
  c.h[0] = (__bf16)a; c.h[1] = (__bf16)b;
  return c.u;
}
__device__ __forceinline__ float exp2x(float x) {
  float r; asm("v_exp_f32 %0, %1" : "=v"(r) : "v"(x)); return r;
}
// k-interleave: within each 32-block store k at position pi(k) so that one
// MFMA fragment [4g..4g+3, 4g+16..4g+19] is one contiguous 16B chunk.
__device__ __forceinline__ int kp32(int k) {
  return (k & ~31) | ((k & 12) << 1) | ((k & 16) >> 2) | (k & 3);
}

// async global->LDS 16B: LDS dest is wave-uniform base + lane*16 (linear).
__device__ __forceinline__ void gload16(const void* g, void* lds) {
  __builtin_amdgcn_global_load_lds(
      (const __attribute__((address_space(1))) unsigned int*)g,
      (__attribute__((address_space(3))) unsigned int*)lds, 16, 0, 0);
}

// single ds_read_b128 fragment from [rows][64] tile: chunk c of row r, XOR swz
__device__ __forceinline__ bf16x8 ldfrag128(const unsigned short* base, int r, int c) {
  union { bf16x8 v; uint4 u; } f;
  f.u = *reinterpret_cast<const uint4*>(base + r * 64 + ((c ^ (r & 7)) << 3));
  return f.v;
}
// ds_read_b128 fragment from [rows][32] tile (BK=32): slot = g ^ ((r>>1)&3).
// 64B rows: (r>>1) swizzle puts exactly 2 lanes per bank-group -> free 2-way.
__device__ __forceinline__ bf16x8 ldfrag32(const unsigned short* base, int r, int g) {
  union { bf16x8 v; uint4 u; } f;
  f.u = *reinterpret_cast<const uint4*>(base + r * 32 + (((g ^ (r >> 1)) & 3) << 3));
  return f.v;
}

// ---------------- LayerNorm x3 + cast to bf16 (k-interleaved output) ---------
__global__ __launch_bounds__(256) void ln3_kernel(
    const float* __restrict__ x0, const float* __restrict__ x1, const float* __restrict__ x2,
    const float* __restrict__ g0, const float* __restrict__ b0,
    const float* __restrict__ g1, const float* __restrict__ b1,
    const float* __restrict__ g2, const float* __restrict__ b2,
    unsigned short* __restrict__ y0, unsigned short* __restrict__ y1,
    unsigned short* __restrict__ y2) {
  const int z = blockIdx.y;
  const float* x = z == 0 ? x0 : z == 1 ? x1 : x2;
  const float* g = z == 0 ? g0 : z == 1 ? g1 : g2;
  const float* bt = z == 0 ? b0 : z == 1 ? b1 : b2;
  unsigned short* y = z == 0 ? y0 : z == 1 ? y1 : y2;
  const int row = blockIdx.x;
  const int t = threadIdx.x;
  const float4 v = reinterpret_cast<const float4*>(x + (size_t)row * HS)[t];
  float s = v.x + v.y + v.z + v.w;
  float s2 = v.x * v.x + v.y * v.y + v.z * v.z + v.w * v.w;
#pragma unroll
  for (int m = 32; m; m >>= 1) { s += __shfl_xor(s, m); s2 += __shfl_xor(s2, m); }
  __shared__ float red[8];
  if ((t & 63) == 0) { red[t >> 6] = s; red[4 + (t >> 6)] = s2; }
  __syncthreads();
  s = red[0] + red[1] + red[2] + red[3];
  s2 = red[4] + red[5] + red[6] + red[7];
  const float mean = s * (1.0f / HS);
  const float var = s2 * (1.0f / HS) - mean * mean;
  const float rs = rsqrtf(var + 1e-5f);
  const float4 gv = reinterpret_cast<const float4*>(g)[t];
  const float4 bv = reinterpret_cast<const float4*>(bt)[t];
  uint2 o;
  o.x = pk2((v.x - mean) * rs * gv.x + bv.x, (v.y - mean) * rs * gv.y + bv.y);
  o.y = pk2((v.z - mean) * rs * gv.z + bv.z, (v.w - mean) * rs * gv.w + bv.w);
  *reinterpret_cast<uint2*>(y + (size_t)row * HS + kp32(4 * t)) = o;
}

// ------------- weight f32 -> bf16 cast, k-interleaved cols, one launch -------
__global__ __launch_bounds__(256) void castw_kernel(
    const float* __restrict__ w0, const float* __restrict__ w1,
    const float* __restrict__ w2, const float* __restrict__ w3,
    unsigned short* __restrict__ o0, unsigned short* __restrict__ o1,
    unsigned short* __restrict__ o2, unsigned short* __restrict__ o3) {
  const int which = blockIdx.x >> 10;
  const float* w = which == 0 ? w0 : which == 1 ? w1 : which == 2 ? w2 : w3;
  unsigned short* o = which == 0 ? o0 : which == 1 ? o1 : which == 2 ? o2 : o3;
  const int i = (blockIdx.x & 1023) * 256 + threadIdx.x;
  float4 v = reinterpret_cast<const float4*>(w)[i];
  uint2 u;
  u.x = pk2(v.x, v.y);
  u.y = pk2(v.z, v.w);
  *reinterpret_cast<uint2*>(o + (size_t)(i >> 8) * 1024 + kp32((i << 2) & 1023)) = u;
}

// stage one 256x32 A-tile (2 chunks/thr) + 128x32 B-tile (1 chunk/thr).
// dest chunk c (row c>>2, slot c&3) holds global chunk (c^(c>>3))&3
// [rule #21: source perm == ldfrag32's read perm].
__device__ __forceinline__ void stage_ab32(const unsigned short* Ab, const unsigned short* Bb,
                                           int kt, unsigned short* ad, unsigned short* bd,
                                           int t) {
#pragma unroll
  for (int i = 0; i < 2; ++i) {
    const int c = i * 512 + t;
    const int col = kt + (((c ^ (c >> 3)) & 3) << 3);
    gload16(Ab + (size_t)(c >> 2) * 1024 + col, ad + c * 8);
  }
  {
    const int c = t;
    const int col = kt + (((c ^ (c >> 3)) & 3) << 3);
    gload16(Bb + (size_t)(c >> 2) * 1024 + col, bd + c * 8);
  }
}

// ------------- QKV projection GEMM: 256x128 tile, BK=32, 8 waves -------------
// acc[4][4] per wave (64x64 output): 8 ds_read_b128 per 16 MFMA = 0.5 r/M
// (R17's acc[4][2] split was 0.75 -> LDS pipe was the most-loaded resource).
// Double-buffered (48KB -> 2 blocks/CU = 16 waves/CU), ONE barrier per step;
// tile k+1's gloads issued post-barrier, drained at the NEXT iteration top.
// XCD swizzle: XCD k owns row-tiles [4k,4k+4) -> A-panel + W L2-resident.
// z=0: Q (QSCALE), z=1: K, z=2: V transposed; outputs k-interleaved.
__global__ __launch_bounds__(512, 4) void gemm_qkv(
    const unsigned short* __restrict__ Aq, const unsigned short* __restrict__ Ak,
    const unsigned short* __restrict__ Av, const unsigned short* __restrict__ Wq,
    const unsigned short* __restrict__ Wk, const unsigned short* __restrict__ Wv,
    unsigned short* __restrict__ Pq, unsigned short* __restrict__ Pk,
    unsigned short* __restrict__ Pv, int zbase) {
  const int z = zbase + blockIdx.z;
  const unsigned short* A = z == 0 ? Aq : z == 1 ? Ak : Av;
  const unsigned short* Bw = z == 0 ? Wq : z == 1 ? Wk : Wv;
  unsigned short* out = z == 0 ? Pq : z == 1 ? Pk : Pv;
  __shared__ unsigned short As[2][256 * 32];   // 16KB each
  __shared__ unsigned short Bs[2][128 * 32];   // 8KB each
  const int t = threadIdx.x;
  const int id = blockIdx.x + 8 * blockIdx.y;  // grid (8,32)
  const int xcd = id & 7, j = id >> 3;         // j in [0,32)
  const int colT = (j & 7) * 128;
  const int rowT = (xcd * 4 + (j >> 3)) * 256;
  const int lane = t & 63;
  const int w = t >> 6;                         // 8 waves: 4M x 2N
  const int wr = (w >> 1) * 64, wc = (w & 1) * 64;
  const int c16 = lane & 15, g = lane >> 4, g4 = g << 2;
  const unsigned short* Ab = A + (size_t)rowT * 1024;
  const unsigned short* Bb = Bw + (size_t)colT * 1024;
  f32x4 acc[4][4] = {};
  stage_ab32(Ab, Bb, 0, As[0], Bs[0], t);
  int buf = 0;
  for (int kt = 0; kt < 32; ++kt) {
    // drain tile kt's loads (issued a full compute phase ago); all reads of
    // the buffer about to be overwritten retired (lgkmcnt 0).
    asm volatile("s_waitcnt vmcnt(0) lgkmcnt(0)" ::: "memory");
    __builtin_amdgcn_s_barrier();
    __builtin_amdgcn_sched_barrier(0);
    if (kt + 1 < 32) stage_ab32(Ab, Bb, (kt + 1) * 32, As[buf ^ 1], Bs[buf ^ 1], t);

    bf16x8 aF[4], bF[4];
#pragma unroll
    for (int m = 0; m < 4; ++m) aF[m] = ldfrag32(As[buf], wr + m * 16 + c16, g);
#pragma unroll
    for (int n = 0; n < 4; ++n) bF[n] = ldfrag32(Bs[buf], wc + n * 16 + c16, g);
    __builtin_amdgcn_s_setprio(1);
#pragma unroll
    for (int m = 0; m < 4; ++m)
#pragma unroll
      for (int n = 0; n < 4; ++n)
        acc[m][n] = __builtin_amdgcn_mfma_f32_16x16x32_bf16(aF[m], bF[n], acc[m][n], 0, 0, 0);
    __builtin_amdgcn_s_setprio(0);
    buf ^= 1;
  }
  const float sc = (z == 0) ? QSCALE : 1.0f;
#pragma unroll
  for (int m = 0; m < 4; ++m) {
#pragma unroll
    for (int n = 0; n < 4; ++n) {
#pragma unroll
      for (int r = 0; r < 4; ++r) {
        const int row = rowT + wr + m * 16 + g4 + r;
        const int col = colT + wc + n * 16 + c16;
        const float val = acc[m][n][r] * sc;
        const int b = row >> 11, s = row & 2047, h = col >> 6, p = col & 63;
        if (z == 2) {
          out[(((size_t)(b * NH + h)) * PS + p) * SS + kp32(s)] = f2bf(val);
        } else {
          out[(((size_t)(b * NH + h)) * SS + s) * PS + kp32(p)] = f2bf(val);
        }
      }
    }
  }
}

// stage one 128x64 A-tile + 128x64 B-tile into given buffers (2+2 gloads/thr).
// dest chunk c (row c>>3, slot c&7) holds global chunk (c^(c>>3))&7.
__device__ __forceinline__ void stage_ab(const unsigned short* Ab, const unsigned short* Bb,
                                         int kt, unsigned short* ad, unsigned short* bd,
                                         int t) {
#pragma unroll
  for (int i = 0; i < 2; ++i) {
    const int c = i * 512 + t;
    const int col = kt + (((c ^ (c >> 3)) & 7) << 3);
    gload16(Ab + (size_t)(c >> 3) * 1024 + col, ad + c * 8);
    gload16(Bb + (size_t)(c >> 3) * 1024 + col, bd + c * 8);
  }
}

// ---------------- fc GEMM: out f32 = acc + bias[col] + resid ----------------
// 8-wave double-buffered 1-barrier loop (R17 config, unchanged).
__global__ __launch_bounds__(512, 4) void gemm_fc(
    const unsigned short* __restrict__ A, const unsigned short* __restrict__ Bw,
    float* __restrict__ out, const float* __restrict__ resid,
    const float* __restrict__ bias) {
  __shared__ unsigned short As[2][128 * 64];
  __shared__ unsigned short Bs[2][128 * 64];
  const int t = threadIdx.x;
  const int id = blockIdx.x + 8 * blockIdx.y;
  const int xcd = id & 7, j = id >> 3;
  const int colT = (j & 7) * 128;
  const int rowT = (xcd * 8 + (j >> 3)) * 128;
  const int lane = t & 63;
  const int w = t >> 6;
  const int wr = (w >> 2) * 64, wc = (w & 3) * 32;
  const int c16 = lane & 15, g = lane >> 4, g4 = g << 2;
  const unsigned short* Ab = A + (size_t)rowT * 1024;
  const unsigned short* Bb = Bw + (size_t)colT * 1024;
  f32x4 acc[4][2] = {};
  stage_ab(Ab, Bb, 0, As[0], Bs[0], t);
  int buf = 0;
  for (int kt = 0; kt < 16; ++kt) {
    asm volatile("s_waitcnt vmcnt(0) lgkmcnt(0)" ::: "memory");
    __builtin_amdgcn_s_barrier();
    __builtin_amdgcn_sched_barrier(0);
    if (kt + 1 < 16) stage_ab(Ab, Bb, (kt + 1) * 64, As[buf ^ 1], Bs[buf ^ 1], t);
#pragma unroll
    for (int kk = 0; kk < 2; ++kk) {
      bf16x8 aF[4], bF[2];
#pragma unroll
      for (int m = 0; m < 4; ++m) aF[m] = ldfrag128(As[buf], wr + m * 16 + c16, kk * 4 + g);
#pragma unroll
      for (int n = 0; n < 2; ++n) bF[n] = ldfrag128(Bs[buf], wc + n * 16 + c16, kk * 4 + g);
      __builtin_amdgcn_s_setprio(1);
#pragma unroll
      for (int m = 0; m < 4; ++m)
#pragma unroll
        for (int n = 0; n < 2; ++n)
          acc[m][n] = __builtin_amdgcn_mfma_f32_16x16x32_bf16(aF[m], bF[n], acc[m][n], 0, 0, 0);
      __builtin_amdgcn_s_setprio(0);
    }
    buf ^= 1;
  }
#pragma unroll
  for (int m = 0; m < 4; ++m) {
#pragma unroll
    for (int n = 0; n < 2; ++n) {
#pragma unroll
      for (int r = 0; r < 4; ++r) {
        const int row = rowT + wr + m * 16 + g4 + r;
        const int col = colT + wc + n * 16 + c16;
        out[(size_t)row * HS + col] =
            acc[m][n][r] + bias[col] + resid[(size_t)row * HS + col];
      }
    }
  }
}

// stage one 128-row K tile + 128-col V^T tile (as 2x 64-sub-tiles) with 512
// threads: dest chunk c (row c>>3, slot c&7) holds global chunk (c^(c>>3))&7.
__device__ __forceinline__ void stage_kv128(const unsigned short* Kb,
                                            const unsigned short* Vb, int tile,
                                            unsigned short* kd, unsigned short* vd,
                                            int t) {
#pragma unroll
  for (int i = 0; i < 2; ++i) {
    const int c = i * 512 + t;
    const int rk = c >> 3;
    const int ck = ((c ^ rk) & 7) << 3;
    gload16(Kb + (size_t)(tile * 128 + rk) * PS + ck, kd + c * 8);
    const int cc = c & 511;
    const int rv = cc >> 3;
    const int cv = ((cc ^ rv) & 7) << 3;
    gload16(Vb + (size_t)rv * SS + tile * 128 + i * 64 + cv, vd + c * 8);
  }
}

// -------- flash attention: swapped QK^T, lane-local P, 32 q-rows/wave --------
// QBLK=256 (8 waves, 512 thr), 2 blocks/CU (16 waves/CU). KVBLK=128, 16
// barriers, 2 LDS buffer-sets (64KB). XCD swizzle keeps K/V L2-resident.
__global__ __launch_bounds__(512, 4) void attn_kernel(
    const unsigned short* __restrict__ Qp, const unsigned short* __restrict__ Kp,
    const unsigned short* __restrict__ Vtg, unsigned short* __restrict__ ctx) {
  __shared__ unsigned short Ks[2][128 * 64];
  __shared__ unsigned short Vs[2][128 * 64];
  const int t = threadIdx.x;
  const int w = t >> 6, lane = t & 63;
  const int c16 = lane & 15, g = lane >> 4, g4 = g << 2;
  const int id = blockIdx.x + 8 * blockIdx.y;
  const int xcd = id & 7, j = id >> 3;  // j in [0,64)
  const int bh = xcd * 8 + (j >> 3);    // b*16 + h
  const int qbase = (j & 7) * 256 + w * 32;
  const unsigned short* Qb = Qp + (size_t)bh * SS * PS;
  const unsigned short* Kb = Kp + (size_t)bh * SS * PS;
  const unsigned short* Vb = Vtg + (size_t)bh * SS * PS;  // [p][s] per head

  union { bf16x8 v; unsigned short s[8]; } ou;
#pragma unroll
  for (int i = 0; i < 8; ++i) ou.s[i] = 0x3F80;  // bf16 1.0
  const bf16x8 onesv = ou.v;

  bf16x8 qF0[2], qF1[2];
#pragma unroll
  for (int kkc = 0; kkc < 2; ++kkc) {
    union { bf16x8 v; uint4 u; } f0, f1;
    f0.u = *reinterpret_cast<const uint4*>(Qb + (size_t)(qbase + c16) * PS + ((kkc * 4 + g) << 3));
    f1.u = *reinterpret_cast<const uint4*>(Qb + (size_t)(qbase + 16 + c16) * PS + ((kkc * 4 + g) << 3));
    qF0[kkc] = f0.v; qF1[kkc] = f1.v;
  }
  f32x4 o0[4] = {}, o1[4] = {};
  f32x4 ol0 = {}, ol1 = {};  // row sums (denominator), same row layout as o0/o1

  // prologue: tile 0 in flight (4 gloads/thread)
  stage_kv128(Kb, Vb, 0, Ks[0], Vs[0], t);

  int buf = 0;
  for (int kt = 0; kt < 16; ++kt) {
    asm volatile("s_waitcnt vmcnt(0) lgkmcnt(0)" ::: "memory");
    __builtin_amdgcn_s_barrier();
    __builtin_amdgcn_sched_barrier(0);
    if (kt + 1 < 16) stage_kv128(Kb, Vb, kt + 1, Ks[buf ^ 1], Vs[buf ^ 1], t);

#pragma unroll
    for (int hh = 0; hh < 2; ++hh) {
      const unsigned short* kh = &Ks[buf][hh * 4096];
      const unsigned short* vh = &Vs[buf][hh * 4096];

      // QK^T swapped: sX[nf] holds P[kv=16nf+g4+reg][q-half X, q=c16]
      f32x4 s0[4] = {}, s1[4] = {};
      __builtin_amdgcn_s_setprio(1);
#pragma unroll
      for (int kkc = 0; kkc < 2; ++kkc)
#pragma unroll
        for (int nf = 0; nf < 4; ++nf) {
          const bf16x8 kf = ldfrag128(kh, nf * 16 + c16, kkc * 4 + g);
          s0[nf] = __builtin_amdgcn_mfma_f32_16x16x32_bf16(kf, qF0[kkc], s0[nf], 0, 0, 0);
          s1[nf] = __builtin_amdgcn_mfma_f32_16x16x32_bf16(kf, qF1[kkc], s1[nf], 0, 0, 0);
        }
      __builtin_amdgcn_s_setprio(0);

      // p = 2^s (no max subtraction; shift-invariant, ranges safe)
#pragma unroll
      for (int nf = 0; nf < 4; ++nf)
#pragma unroll
        for (int r = 0; r < 4; ++r) {
          s0[nf][r] = exp2x(s0[nf][r]);
          s1[nf][r] = exp2x(s1[nf][r]);
        }

      // PV (+ row-sum via ones fragment): P fragments are lane-local
      __builtin_amdgcn_s_setprio(1);
#pragma unroll
      for (int kkc = 0; kkc < 2; ++kkc) {
        union { bf16x8 v; unsigned int u[4]; } pa0, pa1;
        pa0.u[0] = pk2(s0[2 * kkc][0], s0[2 * kkc][1]);
        pa0.u[1] = pk2(s0[2 * kkc][2], s0[2 * kkc][3]);
        pa0.u[2] = pk2(s0[2 * kkc + 1][0], s0[2 * kkc + 1][1]);
        pa0.u[3] = pk2(s0[2 * kkc + 1][2], s0[2 * kkc + 1][3]);
        pa1.u[0] = pk2(s1[2 * kkc][0], s1[2 * kkc][1]);
        pa1.u[1] = pk2(s1[2 * kkc][2], s1[2 * kkc][3]);
        pa1.u[2] = pk2(s1[2 * kkc + 1][0], s1[2 * kkc + 1][1]);
        pa1.u[3] = pk2(s1[2 * kkc + 1][2], s1[2 * kkc + 1][3]);
        ol0 = __builtin_amdgcn_mfma_f32_16x16x32_bf16(pa0.v, onesv, ol0, 0, 0, 0);
        ol1 = __builtin_amdgcn_mfma_f32_16x16x32_bf16(pa1.v, onesv, ol1, 0, 0, 0);
#pragma unroll
        for (int pf = 0; pf < 4; ++pf) {
          const bf16x8 vf = ldfrag128(vh, pf * 16 + c16, kkc * 4 + g);
          o0[pf] = __builtin_amdgcn_mfma_f32_16x16x32_bf16(pa0.v, vf, o0[pf], 0, 0, 0);
          o1[pf] = __builtin_amdgcn_mfma_f32_16x16x32_bf16(pa1.v, vf, o1[pf], 0, 0, 0);
        }
      }
      __builtin_amdgcn_s_setprio(0);
    }

    buf ^= 1;
  }

  float i0[4], i1[4];
#pragma unroll
  for (int r = 0; r < 4; ++r) { i0[r] = 1.0f / ol0[r]; i1[r] = 1.0f / ol1[r]; }
  const int b = bh >> 4, h = bh & 15;
#pragma unroll
  for (int pf = 0; pf < 4; ++pf) {
#pragma unroll
    for (int r = 0; r < 4; ++r) {
      const int col = kp32(h * PS + pf * 16 + c16);  // interleave for fc GEMM
      const int sA = qbase + g4 + r, sB = qbase + 16 + g4 + r;
      ctx[((size_t)(b * SS + sA)) * HS + col] = f2bf(o0[pf][r] * i0[r]);
      ctx[((size_t)(b * SS + sB)) * HS + col] = f2bf(o1[pf][r] * i1[r]);
    }
  }
}

extern "C" void kernel_launch(void* const* d_in, const int* in_sizes, int n_in,
                              void* d_out, int out_size, void* d_ws, size_t ws_size,
                              hipStream_t stream) {
  const float* q = (const float*)d_in[0];
  const float* k = (const float*)d_in[1];
  const float* v = (const float*)d_in[2];
  const float* ln_q_g = (const float*)d_in[3];
  const float* ln_q_b = (const float*)d_in[4];
  const float* ln_k_g = (const float*)d_in[5];
  const float* ln_k_b = (const float*)d_in[6];
  const float* ln_v_g = (const float*)d_in[7];
  const float* ln_v_b = (const float*)d_in[8];
  const float* w_q = (const float*)d_in[9];
  const float* w_k = (const float*)d_in[10];
  const float* w_v = (const float*)d_in[11];
  const float* w_fc = (const float*)d_in[12];
  const float* b_fc = (const float*)d_in[13];

  char* ws = (char*)d_ws;
  const bool merged = ws_size >= ((size_t)104 << 20);

  if (merged) {
    // xq/xk/xv [0,48M); weights [48M,56M); pq/pk/pv [56M,104M); ctx reuses xq
    unsigned short* xq = (unsigned short*)(ws);
    unsigned short* xk = (unsigned short*)(ws + (16 << 20));
    unsigned short* xv = (unsigned short*)(ws + (32 << 20));
    unsigned short* ctx = (unsigned short*)(ws);
    unsigned short* wqb = (unsigned short*)(ws + (48 << 20));
    unsigned short* wkb = (unsigned short*)(ws + (50 << 20));
    unsigned short* wvb = (unsigned short*)(ws + (52 << 20));
    unsigned short* wfcb = (unsigned short*)(ws + (54 << 20));
    unsigned short* pq = (unsigned short*)(ws + (56 << 20));
    unsigned short* pk = (unsigned short*)(ws + (72 << 20));
    unsigned short* pv = (unsigned short*)(ws + (88 << 20));

    castw_kernel<<<4096, 256, 0, stream>>>(w_q, w_k, w_v, w_fc, wqb, wkb, wvb, wfcb);
    ln3_kernel<<<dim3(MTOT, 3), 256, 0, stream>>>(q, k, v, ln_q_g, ln_q_b, ln_k_g,
                                                  ln_k_b, ln_v_g, ln_v_b, xq, xk, xv);
    gemm_qkv<<<dim3(8, 32, 3), 512, 0, stream>>>(xq, xk, xv, wqb, wkb, wvb, pq, pk, pv, 0);
    attn_kernel<<<dim3(8, 64), 512, 0, stream>>>(pq, pk, pv, ctx);
    gemm_fc<<<dim3(8, 64), 512, 0, stream>>>(ctx, wfcb, (float*)d_out, q, b_fc);
  } else {
    // sequential fallback: xln/ctx [0,16M); weights [16M,24M); proj [24M,72M)
    unsigned short* xln = (unsigned short*)(ws);
    unsigned short* ctx = (unsigned short*)(ws);
    unsigned short* wqb = (unsigned short*)(ws + (16 << 20));
    unsigned short* wkb = (unsigned short*)(ws + (18 << 20));
    unsigned short* wvb = (unsigned short*)(ws + (20 << 20));
    unsigned short* wfcb = (unsigned short*)(ws + (22 << 20));
    unsigned short* pq = (unsigned short*)(ws + (24 << 20));
    unsigned short* pk = (unsigned short*)(ws + (40 << 20));
    unsigned short* pv = (unsigned short*)(ws + (56 << 20));

    castw_kernel<<<4096, 256, 0, stream>>>(w_q, w_k, w_v, w_fc, wqb, wkb, wvb, wfcb);
    ln3_kernel<<<dim3(MTOT, 1), 256, 0, stream>>>(q, q, q, ln_q_g, ln_q_b, ln_q_g,
                                                  ln_q_b, ln_q_g, ln_q_b, xln, xln, xln);
    gemm_qkv<<<dim3(8, 32, 1), 512, 0, stream>>>(xln, xln, xln, wqb, wqb, wqb,
                                                 pq, pq, pq, 0);
    ln3_kernel<<<dim3(MTOT, 1), 256, 0, stream>>>(k, k, k, ln_k_g, ln_k_b, ln_k_g,
                                                  ln_k_b, ln_k_g, ln_k_b, xln, xln, xln);
    gemm_qkv<<<dim3(8, 32, 1), 512, 0, stream>>>(xln, xln, xln, wkb, wkb, wkb,
                                                 pk, pk, pk, 1);
    ln3_kernel<<<dim3(MTOT, 1), 256, 0, stream>>>(v, v, v, ln_v_g, ln_v_b, ln_v_g,
                                                  ln_v_b, ln_v_g, ln_v_b, xln, xln, xln);
    gemm_qkv<<<dim3(8, 32, 1), 512, 0, stream>>>(xln, xln, xln, wvb, wvb, wvb,
                                                 pv, pv, pv, 2);
    attn_kernel<<<dim3(8, 64), 512, 0, stream>>>(pq, pk, pv, ctx);
    gemm_fc<<<dim3(8, 64), 512, 0, stream>>>(ctx, wfcb, (float*)d_out, q, b_fc);
  }
}

// Round 19
// 195.187 us; speedup vs baseline: 1.0691x; 1.0691x over previous
//
#include <hip/hip_runtime.h>

#define HS 1024
#define NH 16
#define PS 64
#define SS 2048
#define NB 4
#define MTOT (NB * SS)
// 0.125 (1/sqrt(64)) * log2(e): scores land in log2-domain for v_exp_f32 (2^x)
#define QSCALE 0.18033688011112042f

typedef __bf16 bf16x8 __attribute__((ext_vector_type(8)));
typedef float f32x4 __attribute__((ext_vector_type(4)));

__device__ __forceinline__ unsigned short f2bf(float f) {
  union { __bf16 h; unsigned short u; } c;
  c.h = (__bf16)f;
  return c.u;
}
__device__ __forceinline__ unsigned int pk2(float a, float b) {
  union { __bf16 h[2]; unsigned int u; } c;
  c.h[0] = (__bf16)a; c.h[1] = (__bf16)b;
  return c.u;
}
__device__ __forceinline__ float exp2x(float x) {
  float r; asm("v_exp_f32 %0, %1" : "=v"(r) : "v"(x)); return r;
}
// k-interleave: within each 32-block store k at position pi(k) so that one
// MFMA fragment [4g..4g+3, 4g+16..4g+19] is one contiguous 16B chunk.
__device__ __forceinline__ int kp32(int k) {
  return (k & ~31) | ((k & 12) << 1) | ((k & 16) >> 2) | (k & 3);
}

// async global->LDS 16B: LDS dest is wave-uniform base + lane*16 (linear).
__device__ __forceinline__ void gload16(const void* g, void* lds) {
  __builtin_amdgcn_global_load_lds(
      (const __attribute__((address_space(1))) unsigned int*)g,
      (__attribute__((address_space(3))) unsigned int*)lds, 16, 0, 0);
}

// single ds_read_b128 fragment from [rows][64] tile: chunk c of row r, XOR swz
__device__ __forceinline__ bf16x8 ldfrag128(const unsigned short* base, int r, int c) {
  union { bf16x8 v; uint4 u; } f;
  f.u = *reinterpret_cast<const uint4*>(base + r * 64 + ((c ^ (r & 7)) << 3));
  return f.v;
}

// ---------------- LayerNorm x3 + cast to bf16 (k-interleaved output) ---------
__global__ __launch_bounds__(256) void ln3_kernel(
    const float* __restrict__ x0, const float* __restrict__ x1, const float* __restrict__ x2,
    const float* __restrict__ g0, const float* __restrict__ b0,
    const float* __restrict__ g1, const float* __restrict__ b1,
    const float* __restrict__ g2, const float* __restrict__ b2,
    unsigned short* __restrict__ y0, unsigned short* __restrict__ y1,
    unsigned short* __restrict__ y2) {
  const int z = blockIdx.y;
  const float* x = z == 0 ? x0 : z == 1 ? x1 : x2;
  const float* g = z == 0 ? g0 : z == 1 ? g1 : g2;
  const float* bt = z == 0 ? b0 : z == 1 ? b1 : b2;
  unsigned short* y = z == 0 ? y0 : z == 1 ? y1 : y2;
  const int row = blockIdx.x;
  const int t = threadIdx.x;
  const float4 v = reinterpret_cast<const float4*>(x + (size_t)row * HS)[t];
  float s = v.x + v.y + v.z + v.w;
  float s2 = v.x * v.x + v.y * v.y + v.z * v.z + v.w * v.w;
#pragma unroll
  for (int m = 32; m; m >>= 1) { s += __shfl_xor(s, m); s2 += __shfl_xor(s2, m); }
  __shared__ float red[8];
  if ((t & 63) == 0) { red[t >> 6] = s; red[4 + (t >> 6)] = s2; }
  __syncthreads();
  s = red[0] + red[1] + red[2] + red[3];
  s2 = red[4] + red[5] + red[6] + red[7];
  const float mean = s * (1.0f / HS);
  const float var = s2 * (1.0f / HS) - mean * mean;
  const float rs = rsqrtf(var + 1e-5f);
  const float4 gv = reinterpret_cast<const float4*>(g)[t];
  const float4 bv = reinterpret_cast<const float4*>(bt)[t];
  uint2 o;
  o.x = pk2((v.x - mean) * rs * gv.x + bv.x, (v.y - mean) * rs * gv.y + bv.y);
  o.y = pk2((v.z - mean) * rs * gv.z + bv.z, (v.w - mean) * rs * gv.w + bv.w);
  *reinterpret_cast<uint2*>(y + (size_t)row * HS + kp32(4 * t)) = o;
}

// ------------- weight f32 -> bf16 cast, k-interleaved cols, one launch -------
__global__ __launch_bounds__(256) void castw_kernel(
    const float* __restrict__ w0, const float* __restrict__ w1,
    const float* __restrict__ w2, const float* __restrict__ w3,
    unsigned short* __restrict__ o0, unsigned short* __restrict__ o1,
    unsigned short* __restrict__ o2, unsigned short* __restrict__ o3) {
  const int which = blockIdx.x >> 10;
  const float* w = which == 0 ? w0 : which == 1 ? w1 : which == 2 ? w2 : w3;
  unsigned short* o = which == 0 ? o0 : which == 1 ? o1 : which == 2 ? o2 : o3;
  const int i = (blockIdx.x & 1023) * 256 + threadIdx.x;
  float4 v = reinterpret_cast<const float4*>(w)[i];
  uint2 u;
  u.x = pk2(v.x, v.y);
  u.y = pk2(v.z, v.w);
  *reinterpret_cast<uint2*>(o + (size_t)(i >> 8) * 1024 + kp32((i << 2) & 1023)) = u;
}

// stage one 128x64 A-tile + 128x64 B-tile into given buffers (2+2 gloads/thr).
// dest chunk c (row c>>3, slot c&7) holds global chunk (c^(c>>3))&7
// [rule #21: source perm == ldfrag128's read perm].
__device__ __forceinline__ void stage_ab(const unsigned short* Ab, const unsigned short* Bb,
                                         int kt, unsigned short* ad, unsigned short* bd,
                                         int t) {
#pragma unroll
  for (int i = 0; i < 2; ++i) {
    const int c = i * 512 + t;
    const int col = kt + (((c ^ (c >> 3)) & 7) << 3);
    gload16(Ab + (size_t)(c >> 3) * 1024 + col, ad + c * 8);
    gload16(Bb + (size_t)(c >> 3) * 1024 + col, bd + c * 8);
  }
}

// ------------- QKV projection GEMM: 128x128 tile, 8 waves (512 thr) ----------
// Attn-style loop: double-buffered LDS (64KB -> 2 blocks/CU = 16 waves/CU),
// ONE barrier per K-step; tile k+1's gloads issued after the barrier and
// drained only at the NEXT iteration top -> a full compute phase covers HBM
// latency. (R18's BK=32 variant doubled barrier count -> regressed; BK=64 is
// the measured optimum.) XCD swizzle keeps A-panel + W L2-resident per XCD.
// z=0: Q (QSCALE), z=1: K, z=2: V transposed; outputs k-interleaved.
__global__ __launch_bounds__(512, 4) void gemm_qkv(
    const unsigned short* __restrict__ Aq, const unsigned short* __restrict__ Ak,
    const unsigned short* __restrict__ Av, const unsigned short* __restrict__ Wq,
    const unsigned short* __restrict__ Wk, const unsigned short* __restrict__ Wv,
    unsigned short* __restrict__ Pq, unsigned short* __restrict__ Pk,
    unsigned short* __restrict__ Pv, int zbase) {
  const int z = zbase + blockIdx.z;
  const unsigned short* A = z == 0 ? Aq : z == 1 ? Ak : Av;
  const unsigned short* Bw = z == 0 ? Wq : z == 1 ? Wk : Wv;
  unsigned short* out = z == 0 ? Pq : z == 1 ? Pk : Pv;
  __shared__ unsigned short As[2][128 * 64];
  __shared__ unsigned short Bs[2][128 * 64];
  const int t = threadIdx.x;
  const int id = blockIdx.x + 8 * blockIdx.y;
  const int xcd = id & 7, j = id >> 3;
  const int colT = (j & 7) * 128;
  const int rowT = (xcd * 8 + (j >> 3)) * 128;
  const int lane = t & 63;
  const int w = t >> 6;                         // 8 waves
  const int wr = (w >> 2) * 64, wc = (w & 3) * 32;  // 2M x 4N wave grid
  const int c16 = lane & 15, g = lane >> 4, g4 = g << 2;
  const unsigned short* Ab = A + (size_t)rowT * 1024;
  const unsigned short* Bb = Bw + (size_t)colT * 1024;
  f32x4 acc[4][2] = {};
  // prologue: tile 0 in flight
  stage_ab(Ab, Bb, 0, As[0], Bs[0], t);
  int buf = 0;
  for (int kt = 0; kt < 16; ++kt) {
    // drain tile kt's loads (issued a full compute phase ago); all reads of
    // the buffer about to be overwritten are retired (lgkmcnt 0).
    asm volatile("s_waitcnt vmcnt(0) lgkmcnt(0)" ::: "memory");
    __builtin_amdgcn_s_barrier();
    __builtin_amdgcn_sched_barrier(0);
    if (kt + 1 < 16) stage_ab(Ab, Bb, (kt + 1) * 64, As[buf ^ 1], Bs[buf ^ 1], t);
#pragma unroll
    for (int kk = 0; kk < 2; ++kk) {
      bf16x8 aF[4], bF[2];
#pragma unroll
      for (int m = 0; m < 4; ++m) aF[m] = ldfrag128(As[buf], wr + m * 16 + c16, kk * 4 + g);
#pragma unroll
      for (int n = 0; n < 2; ++n) bF[n] = ldfrag128(Bs[buf], wc + n * 16 + c16, kk * 4 + g);
      __builtin_amdgcn_s_setprio(1);
#pragma unroll
      for (int m = 0; m < 4; ++m)
#pragma unroll
        for (int n = 0; n < 2; ++n)
          acc[m][n] = __builtin_amdgcn_mfma_f32_16x16x32_bf16(aF[m], bF[n], acc[m][n], 0, 0, 0);
      __builtin_amdgcn_s_setprio(0);
    }
    buf ^= 1;
  }
  const float sc = (z == 0) ? QSCALE : 1.0f;
#pragma unroll
  for (int m = 0; m < 4; ++m) {
#pragma unroll
    for (int n = 0; n < 2; ++n) {
#pragma unroll
      for (int r = 0; r < 4; ++r) {
        const int row = rowT + wr + m * 16 + g4 + r;
        const int col = colT + wc + n * 16 + c16;
        const float val = acc[m][n][r] * sc;
        const int b = row >> 11, s = row & 2047, h = col >> 6, p = col & 63;
        if (z == 2) {
          out[(((size_t)(b * NH + h)) * PS + p) * SS + kp32(s)] = f2bf(val);
        } else {
          out[(((size_t)(b * NH + h)) * SS + s) * PS + kp32(p)] = f2bf(val);
        }
      }
    }
  }
}

// ---------------- fc GEMM: out f32 = acc + bias[col] + resid ----------------
// Same 8-wave double-buffered 1-barrier loop as gemm_qkv.
__global__ __launch_bounds__(512, 4) void gemm_fc(
    const unsigned short* __restrict__ A, const unsigned short* __restrict__ Bw,
    float* __restrict__ out, const float* __restrict__ resid,
    const float* __restrict__ bias) {
  __shared__ unsigned short As[2][128 * 64];
  __shared__ unsigned short Bs[2][128 * 64];
  const int t = threadIdx.x;
  const int id = blockIdx.x + 8 * blockIdx.y;
  const int xcd = id & 7, j = id >> 3;
  const int colT = (j & 7) * 128;
  const int rowT = (xcd * 8 + (j >> 3)) * 128;
  const int lane = t & 63;
  const int w = t >> 6;
  const int wr = (w >> 2) * 64, wc = (w & 3) * 32;
  const int c16 = lane & 15, g = lane >> 4, g4 = g << 2;
  const unsigned short* Ab = A + (size_t)rowT * 1024;
  const unsigned short* Bb = Bw + (size_t)colT * 1024;
  f32x4 acc[4][2] = {};
  stage_ab(Ab, Bb, 0, As[0], Bs[0], t);
  int buf = 0;
  for (int kt = 0; kt < 16; ++kt) {
    asm volatile("s_waitcnt vmcnt(0) lgkmcnt(0)" ::: "memory");
    __builtin_amdgcn_s_barrier();
    __builtin_amdgcn_sched_barrier(0);
    if (kt + 1 < 16) stage_ab(Ab, Bb, (kt + 1) * 64, As[buf ^ 1], Bs[buf ^ 1], t);
#pragma unroll
    for (int kk = 0; kk < 2; ++kk) {
      bf16x8 aF[4], bF[2];
#pragma unroll
      for (int m = 0; m < 4; ++m) aF[m] = ldfrag128(As[buf], wr + m * 16 + c16, kk * 4 + g);
#pragma unroll
      for (int n = 0; n < 2; ++n) bF[n] = ldfrag128(Bs[buf], wc + n * 16 + c16, kk * 4 + g);
      __builtin_amdgcn_s_setprio(1);
#pragma unroll
      for (int m = 0; m < 4; ++m)
#pragma unroll
        for (int n = 0; n < 2; ++n)
          acc[m][n] = __builtin_amdgcn_mfma_f32_16x16x32_bf16(aF[m], bF[n], acc[m][n], 0, 0, 0);
      __builtin_amdgcn_s_setprio(0);
    }
    buf ^= 1;
  }
#pragma unroll
  for (int m = 0; m < 4; ++m) {
#pragma unroll
    for (int n = 0; n < 2; ++n) {
#pragma unroll
      for (int r = 0; r < 4; ++r) {
        const int row = rowT + wr + m * 16 + g4 + r;
        const int col = colT + wc + n * 16 + c16;
        out[(size_t)row * HS + col] =
            acc[m][n][r] + bias[col] + resid[(size_t)row * HS + col];
      }
    }
  }
}

// stage one 128-row K tile + 128-col V^T tile (as 2x 64-sub-tiles) with 512
// threads: 2 K chunks + 2 V chunks per thread. dest chunk c (row c>>3, slot
// c&7) holds global chunk (c^(c>>3))&7 [rule #21 == ldfrag128's read perm].
// K sub-tiles: rows [0,64) at kd+[0,4096), rows [64,128) at kd+[4096,8192).
// V sub-tile i covers s-cols [tile*128+i*64, +64) at vd+i*4096.
__device__ __forceinline__ void stage_kv128(const unsigned short* Kb,
                                            const unsigned short* Vb, int tile,
                                            unsigned short* kd, unsigned short* vd,
                                            int t) {
#pragma unroll
  for (int i = 0; i < 2; ++i) {
    const int c = i * 512 + t;
    const int rk = c >> 3;
    const int ck = ((c ^ rk) & 7) << 3;
    gload16(Kb + (size_t)(tile * 128 + rk) * PS + ck, kd + c * 8);
    const int cc = c & 511;
    const int rv = cc >> 3;
    const int cv = ((cc ^ rv) & 7) << 3;
    gload16(Vb + (size_t)rv * SS + tile * 128 + i * 64 + cv, vd + c * 8);
  }
}

// -------- flash attention: swapped QK^T, lane-local P, 32 q-rows/wave --------
// QBLK=256 (8 waves, 512 thr), 2 blocks/CU (16 waves/CU). KVBLK=128: each
// iteration stages a 128-row K/V tile (2x 64-sub-tiles) and computes both
// between ONE barrier pair -> 16 barriers. 2 LDS buffer-sets (64KB).
// XCD swizzle: XCD k owns bh in [8k,8k+8) x 8 q-tiles -> K/V L2-resident.
__global__ __launch_bounds__(512, 4) void attn_kernel(
    const unsigned short* __restrict__ Qp, const unsigned short* __restrict__ Kp,
    const unsigned short* __restrict__ Vtg, unsigned short* __restrict__ ctx) {
  __shared__ unsigned short Ks[2][128 * 64];
  __shared__ unsigned short Vs[2][128 * 64];
  const int t = threadIdx.x;
  const int w = t >> 6, lane = t & 63;
  const int c16 = lane & 15, g = lane >> 4, g4 = g << 2;
  const int id = blockIdx.x + 8 * blockIdx.y;
  const int xcd = id & 7, j = id >> 3;  // j in [0,64)
  const int bh = xcd * 8 + (j >> 3);    // b*16 + h
  const int qbase = (j & 7) * 256 + w * 32;
  const unsigned short* Qb = Qp + (size_t)bh * SS * PS;
  const unsigned short* Kb = Kp + (size_t)bh * SS * PS;
  const unsigned short* Vb = Vtg + (size_t)bh * SS * PS;  // [p][s] per head

  union { bf16x8 v; unsigned short s[8]; } ou;
#pragma unroll
  for (int i = 0; i < 8; ++i) ou.s[i] = 0x3F80;  // bf16 1.0
  const bf16x8 onesv = ou.v;

  bf16x8 qF0[2], qF1[2];
#pragma unroll
  for (int kkc = 0; kkc < 2; ++kkc) {
    union { bf16x8 v; uint4 u; } f0, f1;
    f0.u = *reinterpret_cast<const uint4*>(Qb + (size_t)(qbase + c16) * PS + ((kkc * 4 + g) << 3));
    f1.u = *reinterpret_cast<const uint4*>(Qb + (size_t)(qbase + 16 + c16) * PS + ((kkc * 4 + g) << 3));
    qF0[kkc] = f0.v; qF1[kkc] = f1.v;
  }
  f32x4 o0[4] = {}, o1[4] = {};
  f32x4 ol0 = {}, ol1 = {};  // row sums (denominator), same row layout as o0/o1

  // prologue: tile 0 in flight (4 gloads/thread)
  stage_kv128(Kb, Vb, 0, Ks[0], Vs[0], t);

  int buf = 0;
  for (int kt = 0; kt < 16; ++kt) {
    // tile kt's loads done (issued one full compute phase ago -> covered);
    // all LDS reads of the buffer about to be overwritten retired.
    asm volatile("s_waitcnt vmcnt(0) lgkmcnt(0)" ::: "memory");
    __builtin_amdgcn_s_barrier();
    __builtin_amdgcn_sched_barrier(0);
    if (kt + 1 < 16) stage_kv128(Kb, Vb, kt + 1, Ks[buf ^ 1], Vs[buf ^ 1], t);

#pragma unroll
    for (int hh = 0; hh < 2; ++hh) {
      const unsigned short* kh = &Ks[buf][hh * 4096];
      const unsigned short* vh = &Vs[buf][hh * 4096];

      // QK^T swapped: sX[nf] holds P[kv=16nf+g4+reg][q-half X, q=c16]
      f32x4 s0[4] = {}, s1[4] = {};
      __builtin_amdgcn_s_setprio(1);
#pragma unroll
      for (int kkc = 0; kkc < 2; ++kkc)
#pragma unroll
        for (int nf = 0; nf < 4; ++nf) {
          const bf16x8 kf = ldfrag128(kh, nf * 16 + c16, kkc * 4 + g);
          s0[nf] = __builtin_amdgcn_mfma_f32_16x16x32_bf16(kf, qF0[kkc], s0[nf], 0, 0, 0);
          s1[nf] = __builtin_amdgcn_mfma_f32_16x16x32_bf16(kf, qF1[kkc], s1[nf], 0, 0, 0);
        }
      __builtin_amdgcn_s_setprio(0);

      // p = 2^s (no max subtraction; shift-invariant, ranges safe)
#pragma unroll
      for (int nf = 0; nf < 4; ++nf)
#pragma unroll
        for (int r = 0; r < 4; ++r) {
          s0[nf][r] = exp2x(s0[nf][r]);
          s1[nf][r] = exp2x(s1[nf][r]);
        }

      // PV (+ row-sum via ones fragment): P fragments are lane-local
      __builtin_amdgcn_s_setprio(1);
#pragma unroll
      for (int kkc = 0; kkc < 2; ++kkc) {
        union { bf16x8 v; unsigned int u[4]; } pa0, pa1;
        pa0.u[0] = pk2(s0[2 * kkc][0], s0[2 * kkc][1]);
        pa0.u[1] = pk2(s0[2 * kkc][2], s0[2 * kkc][3]);
        pa0.u[2] = pk2(s0[2 * kkc + 1][0], s0[2 * kkc + 1][1]);
        pa0.u[3] = pk2(s0[2 * kkc + 1][2], s0[2 * kkc + 1][3]);
        pa1.u[0] = pk2(s1[2 * kkc][0], s1[2 * kkc][1]);
        pa1.u[1] = pk2(s1[2 * kkc][2], s1[2 * kkc][3]);
        pa1.u[2] = pk2(s1[2 * kkc + 1][0], s1[2 * kkc + 1][1]);
        pa1.u[3] = pk2(s1[2 * kkc + 1][2], s1[2 * kkc + 1][3]);
        ol0 = __builtin_amdgcn_mfma_f32_16x16x32_bf16(pa0.v, onesv, ol0, 0, 0, 0);
        ol1 = __builtin_amdgcn_mfma_f32_16x16x32_bf16(pa1.v, onesv, ol1, 0, 0, 0);
#pragma unroll
        for (int pf = 0; pf < 4; ++pf) {
          const bf16x8 vf = ldfrag128(vh, pf * 16 + c16, kkc * 4 + g);
          o0[pf] = __builtin_amdgcn_mfma_f32_16x16x32_bf16(pa0.v, vf, o0[pf], 0, 0, 0);
          o1[pf] = __builtin_amdgcn_mfma_f32_16x16x32_bf16(pa1.v, vf, o1[pf], 0, 0, 0);
        }
      }
      __builtin_amdgcn_s_setprio(0);
    }

    buf ^= 1;
  }

  float i0[4], i1[4];
#pragma unroll
  for (int r = 0; r < 4; ++r) { i0[r] = 1.0f / ol0[r]; i1[r] = 1.0f / ol1[r]; }
  const int b = bh >> 4, h = bh & 15;
#pragma unroll
  for (int pf = 0; pf < 4; ++pf) {
#pragma unroll
    for (int r = 0; r < 4; ++r) {
      const int col = kp32(h * PS + pf * 16 + c16);  // interleave for fc GEMM
      const int sA = qbase + g4 + r, sB = qbase + 16 + g4 + r;
      ctx[((size_t)(b * SS + sA)) * HS + col] = f2bf(o0[pf][r] * i0[r]);
      ctx[((size_t)(b * SS + sB)) * HS + col] = f2bf(o1[pf][r] * i1[r]);
    }
  }
}

extern "C" void kernel_launch(void* const* d_in, const int* in_sizes, int n_in,
                              void* d_out, int out_size, void* d_ws, size_t ws_size,
                              hipStream_t stream) {
  const float* q = (const float*)d_in[0];
  const float* k = (const float*)d_in[1];
  const float* v = (const float*)d_in[2];
  const float* ln_q_g = (const float*)d_in[3];
  const float* ln_q_b = (const float*)d_in[4];
  const float* ln_k_g = (const float*)d_in[5];
  const float* ln_k_b = (const float*)d_in[6];
  const float* ln_v_g = (const float*)d_in[7];
  const float* ln_v_b = (const float*)d_in[8];
  const float* w_q = (const float*)d_in[9];
  const float* w_k = (const float*)d_in[10];
  const float* w_v = (const float*)d_in[11];
  const float* w_fc = (const float*)d_in[12];
  const float* b_fc = (const float*)d_in[13];

  char* ws = (char*)d_ws;
  const bool merged = ws_size >= ((size_t)104 << 20);

  if (merged) {
    // xq/xk/xv [0,48M); weights [48M,56M); pq/pk/pv [56M,104M); ctx reuses xq
    unsigned short* xq = (unsigned short*)(ws);
    unsigned short* xk = (unsigned short*)(ws + (16 << 20));
    unsigned short* xv = (unsigned short*)(ws + (32 << 20));
    unsigned short* ctx = (unsigned short*)(ws);
    unsigned short* wqb = (unsigned short*)(ws + (48 << 20));
    unsigned short* wkb = (unsigned short*)(ws + (50 << 20));
    unsigned short* wvb = (unsigned short*)(ws + (52 << 20));
    unsigned short* wfcb = (unsigned short*)(ws + (54 << 20));
    unsigned short* pq = (unsigned short*)(ws + (56 << 20));
    unsigned short* pk = (unsigned short*)(ws + (72 << 20));
    unsigned short* pv = (unsigned short*)(ws + (88 << 20));

    castw_kernel<<<4096, 256, 0, stream>>>(w_q, w_k, w_v, w_fc, wqb, wkb, wvb, wfcb);
    ln3_kernel<<<dim3(MTOT, 3), 256, 0, stream>>>(q, k, v, ln_q_g, ln_q_b, ln_k_g,
                                                  ln_k_b, ln_v_g, ln_v_b, xq, xk, xv);
    gemm_qkv<<<dim3(8, 64, 3), 512, 0, stream>>>(xq, xk, xv, wqb, wkb, wvb, pq, pk, pv, 0);
    attn_kernel<<<dim3(8, 64), 512, 0, stream>>>(pq, pk, pv, ctx);
    gemm_fc<<<dim3(8, 64), 512, 0, stream>>>(ctx, wfcb, (float*)d_out, q, b_fc);
  } else {
    // sequential fallback: xln/ctx [0,16M); weights [16M,24M); proj [24M,72M)
    unsigned short* xln = (unsigned short*)(ws);
    unsigned short* ctx = (unsigned short*)(ws);
    unsigned short* wqb = (unsigned short*)(ws + (16 << 20));
    unsigned short* wkb = (unsigned short*)(ws + (18 << 20));
    unsigned short* wvb = (unsigned short*)(ws + (20 << 20));
    unsigned short* wfcb = (unsigned short*)(ws + (22 << 20));
    unsigned short* pq = (unsigned short*)(ws + (24 << 20));
    unsigned short* pk = (unsigned short*)(ws + (40 << 20));
    unsigned short* pv = (unsigned short*)(ws + (56 << 20));

    castw_kernel<<<4096, 256, 0, stream>>>(w_q, w_k, w_v, w_fc, wqb, wkb, wvb, wfcb);
    ln3_kernel<<<dim3(MTOT, 1), 256, 0, stream>>>(q, q, q, ln_q_g, ln_q_b, ln_q_g,
                                                  ln_q_b, ln_q_g, ln_q_b, xln, xln, xln);
    gemm_qkv<<<dim3(8, 64, 1), 512, 0, stream>>>(xln, xln, xln, wqb, wqb, wqb,
                                                 pq, pq, pq, 0);
    ln3_kernel<<<dim3(MTOT, 1), 256, 0, stream>>>(k, k, k, ln_k_g, ln_k_b, ln_k_g,
                                                  ln_k_b, ln_k_g, ln_k_b, xln, xln, xln);
    gemm_qkv<<<dim3(8, 64, 1), 512, 0, stream>>>(xln, xln, xln, wkb, wkb, wkb,
                                                 pk, pk, pk, 1);
    ln3_kernel<<<dim3(MTOT, 1), 256, 0, stream>>>(v, v, v, ln_v_g, ln_v_b, ln_v_g,
                                                  ln_v_b, ln_v_g, ln_v_b, xln, xln, xln);
    gemm_qkv<<<dim3(8, 64, 1), 512, 0, stream>>>(xln, xln, xln, wvb, wvb, wvb,
                                                 pv, pv, pv, 2);
    attn_kernel<<<dim3(8, 64), 512, 0, stream>>>(pq, pk, pv, ctx);
    gemm_fc<<<dim3(8, 64), 512, 0, stream>>>(ctx, wfcb, (float*)d_out, q, b_fc);
  }
}

// Round 20
// 184.243 us; speedup vs baseline: 1.1327x; 1.0594x over previous
//
#include <hip/hip_runtime.h>

#define HS 1024
#define NH 16
#define PS 64
#define SS 2048
#define NB 4
#define MTOT (NB * SS)
// 0.125 (1/sqrt(64)) * log2(e): scores land in log2-domain for v_exp_f32 (2^x)
#define QSCALE 0.18033688011112042f

typedef __bf16 bf16x8 __attribute__((ext_vector_type(8)));
typedef float f32x4 __attribute__((ext_vector_type(4)));

__device__ __forceinline__ unsigned short f2bf(float f) {
  union { __bf16 h; unsigned short u; } c;
  c.h = (__bf16)f;
  return c.u;
}
__device__ __forceinline__ unsigned int pk2(float a, float b) {
  union { __bf16 h[2]; unsigned int u; } c;
  c.h[0] = (__bf16)a; c.h[1] = (__bf16)b;
  return c.u;
}
__device__ __forceinline__ float exp2x(float x) {
  float r; asm("v_exp_f32 %0, %1" : "=v"(r) : "v"(x)); return r;
}
// k-interleave: within each 32-block store k at position pi(k) so that one
// MFMA fragment [4g..4g+3, 4g+16..4g+19] is one contiguous 16B chunk.
__device__ __forceinline__ int kp32(int k) {
  return (k & ~31) | ((k & 12) << 1) | ((k & 16) >> 2) | (k & 3);
}

// async global->LDS 16B: LDS dest is wave-uniform base + lane*16 (linear).
__device__ __forceinline__ void gload16(const void* g, void* lds) {
  __builtin_amdgcn_global_load_lds(
      (const __attribute__((address_space(1))) unsigned int*)g,
      (__attribute__((address_space(3))) unsigned int*)lds, 16, 0, 0);
}

// single ds_read_b128 fragment from [rows][64] tile: chunk c of row r, XOR swz
__device__ __forceinline__ bf16x8 ldfrag128(const unsigned short* base, int r, int c) {
  union { bf16x8 v; uint4 u; } f;
  f.u = *reinterpret_cast<const uint4*>(base + r * 64 + ((c ^ (r & 7)) << 3));
  return f.v;
}

// ---------------- LayerNorm x3 + cast to bf16 (k-interleaved output) ---------
__global__ __launch_bounds__(256) void ln3_kernel(
    const float* __restrict__ x0, const float* __restrict__ x1, const float* __restrict__ x2,
    const float* __restrict__ g0, const float* __restrict__ b0,
    const float* __restrict__ g1, const float* __restrict__ b1,
    const float* __restrict__ g2, const float* __restrict__ b2,
    unsigned short* __restrict__ y0, unsigned short* __restrict__ y1,
    unsigned short* __restrict__ y2) {
  const int z = blockIdx.y;
  const float* x = z == 0 ? x0 : z == 1 ? x1 : x2;
  const float* g = z == 0 ? g0 : z == 1 ? g1 : g2;
  const float* bt = z == 0 ? b0 : z == 1 ? b1 : b2;
  unsigned short* y = z == 0 ? y0 : z == 1 ? y1 : y2;
  const int row = blockIdx.x;
  const int t = threadIdx.x;
  const float4 v = reinterpret_cast<const float4*>(x + (size_t)row * HS)[t];
  float s = v.x + v.y + v.z + v.w;
  float s2 = v.x * v.x + v.y * v.y + v.z * v.z + v.w * v.w;
#pragma unroll
  for (int m = 32; m; m >>= 1) { s += __shfl_xor(s, m); s2 += __shfl_xor(s2, m); }
  __shared__ float red[8];
  if ((t & 63) == 0) { red[t >> 6] = s; red[4 + (t >> 6)] = s2; }
  __syncthreads();
  s = red[0] + red[1] + red[2] + red[3];
  s2 = red[4] + red[5] + red[6] + red[7];
  const float mean = s * (1.0f / HS);
  const float var = s2 * (1.0f / HS) - mean * mean;
  const float rs = rsqrtf(var + 1e-5f);
  const float4 gv = reinterpret_cast<const float4*>(g)[t];
  const float4 bv = reinterpret_cast<const float4*>(bt)[t];
  uint2 o;
  o.x = pk2((v.x - mean) * rs * gv.x + bv.x, (v.y - mean) * rs * gv.y + bv.y);
  o.y = pk2((v.z - mean) * rs * gv.z + bv.z, (v.w - mean) * rs * gv.w + bv.w);
  *reinterpret_cast<uint2*>(y + (size_t)row * HS + kp32(4 * t)) = o;
}

// ------------- weight f32 -> bf16 cast, k-interleaved cols, one launch -------
__global__ __launch_bounds__(256) void castw_kernel(
    const float* __restrict__ w0, const float* __restrict__ w1,
    const float* __restrict__ w2, const float* __restrict__ w3,
    unsigned short* __restrict__ o0, unsigned short* __restrict__ o1,
    unsigned short* __restrict__ o2, unsigned short* __restrict__ o3) {
  const int which = blockIdx.x >> 10;
  const float* w = which == 0 ? w0 : which == 1 ? w1 : which == 2 ? w2 : w3;
  unsigned short* o = which == 0 ? o0 : which == 1 ? o1 : which == 2 ? o2 : o3;
  const int i = (blockIdx.x & 1023) * 256 + threadIdx.x;
  float4 v = reinterpret_cast<const float4*>(w)[i];
  uint2 u;
  u.x = pk2(v.x, v.y);
  u.y = pk2(v.z, v.w);
  *reinterpret_cast<uint2*>(o + (size_t)(i >> 8) * 1024 + kp32((i << 2) & 1023)) = u;
}

// stage one 128x64 A-tile + 128x64 B-tile into given buffers (2+2 gloads/thr).
// dest chunk c (row c>>3, slot c&7) holds global chunk (c^(c>>3))&7
// [rule #21: source perm == ldfrag128's read perm].
__device__ __forceinline__ void stage_ab(const unsigned short* Ab, const unsigned short* Bb,
                                         int kt, unsigned short* ad, unsigned short* bd,
                                         int t) {
#pragma unroll
  for (int i = 0; i < 2; ++i) {
    const int c = i * 512 + t;
    const int col = kt + (((c ^ (c >> 3)) & 7) << 3);
    gload16(Ab + (size_t)(c >> 3) * 1024 + col, ad + c * 8);
    gload16(Bb + (size_t)(c >> 3) * 1024 + col, bd + c * 8);
  }
}

// ------------- QKV projection GEMM: 128x128 tile, 8 waves (512 thr) ----------
// Attn-style loop: double-buffered LDS (64KB -> 2 blocks/CU = 16 waves/CU),
// ONE barrier per K-step; tile k+1's gloads issued after the barrier and
// drained only at the NEXT iteration top -> a full compute phase covers HBM
// latency. z=2 (V) epilogue: each thread owns a full 16B interleaved chunk
// (positions 8g+4(m&1)+r of block m>>1) -> 4 uint4 stores instead of 32
// scalar 2B stores 4KB apart (was ~1/3 of the V-slice time).
// z=0: Q (QSCALE), z=1: K, z=2: V transposed; outputs k-interleaved.
__global__ __launch_bounds__(512, 4) void gemm_qkv(
    const unsigned short* __restrict__ Aq, const unsigned short* __restrict__ Ak,
    const unsigned short* __restrict__ Av, const unsigned short* __restrict__ Wq,
    const unsigned short* __restrict__ Wk, const unsigned short* __restrict__ Wv,
    unsigned short* __restrict__ Pq, unsigned short* __restrict__ Pk,
    unsigned short* __restrict__ Pv, int zbase) {
  const int z = zbase + blockIdx.z;
  const unsigned short* A = z == 0 ? Aq : z == 1 ? Ak : Av;
  const unsigned short* Bw = z == 0 ? Wq : z == 1 ? Wk : Wv;
  unsigned short* out = z == 0 ? Pq : z == 1 ? Pk : Pv;
  __shared__ unsigned short As[2][128 * 64];
  __shared__ unsigned short Bs[2][128 * 64];
  const int t = threadIdx.x;
  const int id = blockIdx.x + 8 * blockIdx.y;
  const int xcd = id & 7, j = id >> 3;
  const int colT = (j & 7) * 128;
  const int rowT = (xcd * 8 + (j >> 3)) * 128;
  const int lane = t & 63;
  const int w = t >> 6;                         // 8 waves
  const int wr = (w >> 2) * 64, wc = (w & 3) * 32;  // 2M x 4N wave grid
  const int c16 = lane & 15, g = lane >> 4, g4 = g << 2;
  const unsigned short* Ab = A + (size_t)rowT * 1024;
  const unsigned short* Bb = Bw + (size_t)colT * 1024;
  f32x4 acc[4][2] = {};
  // prologue: tile 0 in flight
  stage_ab(Ab, Bb, 0, As[0], Bs[0], t);
  int buf = 0;
  for (int kt = 0; kt < 16; ++kt) {
    // drain tile kt's loads (issued a full compute phase ago); all reads of
    // the buffer about to be overwritten are retired (lgkmcnt 0).
    asm volatile("s_waitcnt vmcnt(0) lgkmcnt(0)" ::: "memory");
    __builtin_amdgcn_s_barrier();
    __builtin_amdgcn_sched_barrier(0);
    if (kt + 1 < 16) stage_ab(Ab, Bb, (kt + 1) * 64, As[buf ^ 1], Bs[buf ^ 1], t);
#pragma unroll
    for (int kk = 0; kk < 2; ++kk) {
      bf16x8 aF[4], bF[2];
#pragma unroll
      for (int m = 0; m < 4; ++m) aF[m] = ldfrag128(As[buf], wr + m * 16 + c16, kk * 4 + g);
#pragma unroll
      for (int n = 0; n < 2; ++n) bF[n] = ldfrag128(Bs[buf], wc + n * 16 + c16, kk * 4 + g);
      __builtin_amdgcn_s_setprio(1);
#pragma unroll
      for (int m = 0; m < 4; ++m)
#pragma unroll
        for (int n = 0; n < 2; ++n)
          acc[m][n] = __builtin_amdgcn_mfma_f32_16x16x32_bf16(aF[m], bF[n], acc[m][n], 0, 0, 0);
      __builtin_amdgcn_s_setprio(0);
    }
    buf ^= 1;
  }
  if (z == 2) {
    // V^T vectorized epilogue: acc[2j][n][0..3] + acc[2j+1][n][0..3] form the
    // 16B chunk at global interleaved offset srow + 32j + 8g of column p.
    const int bb = rowT >> 11;
    const int srow = (rowT & 2047) + wr;
#pragma unroll
    for (int jj = 0; jj < 2; ++jj) {
#pragma unroll
      for (int n = 0; n < 2; ++n) {
        const int col = colT + wc + n * 16 + c16;
        const int h = col >> 6, p = col & 63;
        union { uint4 u4; unsigned int u[4]; } vv;
        vv.u[0] = pk2(acc[2 * jj][n][0], acc[2 * jj][n][1]);
        vv.u[1] = pk2(acc[2 * jj][n][2], acc[2 * jj][n][3]);
        vv.u[2] = pk2(acc[2 * jj + 1][n][0], acc[2 * jj + 1][n][1]);
        vv.u[3] = pk2(acc[2 * jj + 1][n][2], acc[2 * jj + 1][n][3]);
        *reinterpret_cast<uint4*>(out + (((size_t)(bb * NH + h)) * PS + p) * SS +
                                  srow + 32 * jj + 8 * g) = vv.u4;
      }
    }
  } else {
    const float sc = (z == 0) ? QSCALE : 1.0f;
#pragma unroll
    for (int m = 0; m < 4; ++m) {
#pragma unroll
      for (int n = 0; n < 2; ++n) {
#pragma unroll
        for (int r = 0; r < 4; ++r) {
          const int row = rowT + wr + m * 16 + g4 + r;
          const int col = colT + wc + n * 16 + c16;
          const float val = acc[m][n][r] * sc;
          const int b = row >> 11, s = row & 2047, h = col >> 6, p = col & 63;
          out[(((size_t)(b * NH + h)) * SS + s) * PS + kp32(p)] = f2bf(val);
        }
      }
    }
  }
}

// ---------------- fc GEMM: out f32 = acc + bias[col] + resid ----------------
// Same 8-wave double-buffered 1-barrier loop as gemm_qkv.
__global__ __launch_bounds__(512, 4) void gemm_fc(
    const unsigned short* __restrict__ A, const unsigned short* __restrict__ Bw,
    float* __restrict__ out, const float* __restrict__ resid,
    const float* __restrict__ bias) {
  __shared__ unsigned short As[2][128 * 64];
  __shared__ unsigned short Bs[2][128 * 64];
  const int t = threadIdx.x;
  const int id = blockIdx.x + 8 * blockIdx.y;
  const int xcd = id & 7, j = id >> 3;
  const int colT = (j & 7) * 128;
  const int rowT = (xcd * 8 + (j >> 3)) * 128;
  const int lane = t & 63;
  const int w = t >> 6;
  const int wr = (w >> 2) * 64, wc = (w & 3) * 32;
  const int c16 = lane & 15, g = lane >> 4, g4 = g << 2;
  const unsigned short* Ab = A + (size_t)rowT * 1024;
  const unsigned short* Bb = Bw + (size_t)colT * 1024;
  f32x4 acc[4][2] = {};
  stage_ab(Ab, Bb, 0, As[0], Bs[0], t);
  int buf = 0;
  for (int kt = 0; kt < 16; ++kt) {
    asm volatile("s_waitcnt vmcnt(0) lgkmcnt(0)" ::: "memory");
    __builtin_amdgcn_s_barrier();
    __builtin_amdgcn_sched_barrier(0);
    if (kt + 1 < 16) stage_ab(Ab, Bb, (kt + 1) * 64, As[buf ^ 1], Bs[buf ^ 1], t);
#pragma unroll
    for (int kk = 0; kk < 2; ++kk) {
      bf16x8 aF[4], bF[2];
#pragma unroll
      for (int m = 0; m < 4; ++m) aF[m] = ldfrag128(As[buf], wr + m * 16 + c16, kk * 4 + g);
#pragma unroll
      for (int n = 0; n < 2; ++n) bF[n] = ldfrag128(Bs[buf], wc + n * 16 + c16, kk * 4 + g);
      __builtin_amdgcn_s_setprio(1);
#pragma unroll
      for (int m = 0; m < 4; ++m)
#pragma unroll
        for (int n = 0; n < 2; ++n)
          acc[m][n] = __builtin_amdgcn_mfma_f32_16x16x32_bf16(aF[m], bF[n], acc[m][n], 0, 0, 0);
      __builtin_amdgcn_s_setprio(0);
    }
    buf ^= 1;
  }
#pragma unroll
  for (int m = 0; m < 4; ++m) {
#pragma unroll
    for (int n = 0; n < 2; ++n) {
#pragma unroll
      for (int r = 0; r < 4; ++r) {
        const int row = rowT + wr + m * 16 + g4 + r;
        const int col = colT + wc + n * 16 + c16;
        out[(size_t)row * HS + col] =
            acc[m][n][r] + bias[col] + resid[(size_t)row * HS + col];
      }
    }
  }
}

// stage one 128-row K tile + 128-col V^T tile (as 2x 64-sub-tiles) with 512
// threads: 2 K chunks + 2 V chunks per thread. dest chunk c (row c>>3, slot
// c&7) holds global chunk (c^(c>>3))&7 [rule #21 == ldfrag128's read perm].
__device__ __forceinline__ void stage_kv128(const unsigned short* Kb,
                                            const unsigned short* Vb, int tile,
                                            unsigned short* kd, unsigned short* vd,
                                            int t) {
#pragma unroll
  for (int i = 0; i < 2; ++i) {
    const int c = i * 512 + t;
    const int rk = c >> 3;
    const int ck = ((c ^ rk) & 7) << 3;
    gload16(Kb + (size_t)(tile * 128 + rk) * PS + ck, kd + c * 8);
    const int cc = c & 511;
    const int rv = cc >> 3;
    const int cv = ((cc ^ rv) & 7) << 3;
    gload16(Vb + (size_t)rv * SS + tile * 128 + i * 64 + cv, vd + c * 8);
  }
}

// -------- flash attention: swapped QK^T, lane-local P, 32 q-rows/wave --------
// QBLK=256 (8 waves, 512 thr), 2 blocks/CU (16 waves/CU). KVBLK=128, 16
// barriers, 2 LDS buffer-sets (64KB). XCD swizzle keeps K/V L2-resident.
__global__ __launch_bounds__(512, 4) void attn_kernel(
    const unsigned short* __restrict__ Qp, const unsigned short* __restrict__ Kp,
    const unsigned short* __restrict__ Vtg, unsigned short* __restrict__ ctx) {
  __shared__ unsigned short Ks[2][128 * 64];
  __shared__ unsigned short Vs[2][128 * 64];
  const int t = threadIdx.x;
  const int w = t >> 6, lane = t & 63;
  const int c16 = lane & 15, g = lane >> 4, g4 = g << 2;
  const int id = blockIdx.x + 8 * blockIdx.y;
  const int xcd = id & 7, j = id >> 3;  // j in [0,64)
  const int bh = xcd * 8 + (j >> 3);    // b*16 + h
  const int qbase = (j & 7) * 256 + w * 32;
  const unsigned short* Qb = Qp + (size_t)bh * SS * PS;
  const unsigned short* Kb = Kp + (size_t)bh * SS * PS;
  const unsigned short* Vb = Vtg + (size_t)bh * SS * PS;  // [p][s] per head

  union { bf16x8 v; unsigned short s[8]; } ou;
#pragma unroll
  for (int i = 0; i < 8; ++i) ou.s[i] = 0x3F80;  // bf16 1.0
  const bf16x8 onesv = ou.v;

  bf16x8 qF0[2], qF1[2];
#pragma unroll
  for (int kkc = 0; kkc < 2; ++kkc) {
    union { bf16x8 v; uint4 u; } f0, f1;
    f0.u = *reinterpret_cast<const uint4*>(Qb + (size_t)(qbase + c16) * PS + ((kkc * 4 + g) << 3));
    f1.u = *reinterpret_cast<const uint4*>(Qb + (size_t)(qbase + 16 + c16) * PS + ((kkc * 4 + g) << 3));
    qF0[kkc] = f0.v; qF1[kkc] = f1.v;
  }
  f32x4 o0[4] = {}, o1[4] = {};
  f32x4 ol0 = {}, ol1 = {};  // row sums (denominator), same row layout as o0/o1

  // prologue: tile 0 in flight (4 gloads/thread)
  stage_kv128(Kb, Vb, 0, Ks[0], Vs[0], t);

  int buf = 0;
  for (int kt = 0; kt < 16; ++kt) {
    // tile kt's loads done (issued one full compute phase ago -> covered);
    // all LDS reads of the buffer about to be overwritten retired.
    asm volatile("s_waitcnt vmcnt(0) lgkmcnt(0)" ::: "memory");
    __builtin_amdgcn_s_barrier();
    __builtin_amdgcn_sched_barrier(0);
    if (kt + 1 < 16) stage_kv128(Kb, Vb, kt + 1, Ks[buf ^ 1], Vs[buf ^ 1], t);

#pragma unroll
    for (int hh = 0; hh < 2; ++hh) {
      const unsigned short* kh = &Ks[buf][hh * 4096];
      const unsigned short* vh = &Vs[buf][hh * 4096];

      // QK^T swapped: sX[nf] holds P[kv=16nf+g4+reg][q-half X, q=c16]
      f32x4 s0[4] = {}, s1[4] = {};
      __builtin_amdgcn_s_setprio(1);
#pragma unroll
      for (int kkc = 0; kkc < 2; ++kkc)
#pragma unroll
        for (int nf = 0; nf < 4; ++nf) {
          const bf16x8 kf = ldfrag128(kh, nf * 16 + c16, kkc * 4 + g);
          s0[nf] = __builtin_amdgcn_mfma_f32_16x16x32_bf16(kf, qF0[kkc], s0[nf], 0, 0, 0);
          s1[nf] = __builtin_amdgcn_mfma_f32_16x16x32_bf16(kf, qF1[kkc], s1[nf], 0, 0, 0);
        }
      __builtin_amdgcn_s_setprio(0);

      // p = 2^s (no max subtraction; shift-invariant, ranges safe)
#pragma unroll
      for (int nf = 0; nf < 4; ++nf)
#pragma unroll
        for (int r = 0; r < 4; ++r) {
          s0[nf][r] = exp2x(s0[nf][r]);
          s1[nf][r] = exp2x(s1[nf][r]);
        }

      // PV (+ row-sum via ones fragment): P fragments are lane-local
      __builtin_amdgcn_s_setprio(1);
#pragma unroll
      for (int kkc = 0; kkc < 2; ++kkc) {
        union { bf16x8 v; unsigned int u[4]; } pa0, pa1;
        pa0.u[0] = pk2(s0[2 * kkc][0], s0[2 * kkc][1]);
        pa0.u[1] = pk2(s0[2 * kkc][2], s0[2 * kkc][3]);
        pa0.u[2] = pk2(s0[2 * kkc + 1][0], s0[2 * kkc + 1][1]);
        pa0.u[3] = pk2(s0[2 * kkc + 1][2], s0[2 * kkc + 1][3]);
        pa1.u[0] = pk2(s1[2 * kkc][0], s1[2 * kkc][1]);
        pa1.u[1] = pk2(s1[2 * kkc][2], s1[2 * kkc][3]);
        pa1.u[2] = pk2(s1[2 * kkc + 1][0], s1[2 * kkc + 1][1]);
        pa1.u[3] = pk2(s1[2 * kkc + 1][2], s1[2 * kkc + 1][3]);
        ol0 = __builtin_amdgcn_mfma_f32_16x16x32_bf16(pa0.v, onesv, ol0, 0, 0, 0);
        ol1 = __builtin_amdgcn_mfma_f32_16x16x32_bf16(pa1.v, onesv, ol1, 0, 0, 0);
#pragma unroll
        for (int pf = 0; pf < 4; ++pf) {
          const bf16x8 vf = ldfrag128(vh, pf * 16 + c16, kkc * 4 + g);
          o0[pf] = __builtin_amdgcn_mfma_f32_16x16x32_bf16(pa0.v, vf, o0[pf], 0, 0, 0);
          o1[pf] = __builtin_amdgcn_mfma_f32_16x16x32_bf16(pa1.v, vf, o1[pf], 0, 0, 0);
        }
      }
      __builtin_amdgcn_s_setprio(0);
    }

    buf ^= 1;
  }

  float i0[4], i1[4];
#pragma unroll
  for (int r = 0; r < 4; ++r) { i0[r] = 1.0f / ol0[r]; i1[r] = 1.0f / ol1[r]; }
  const int b = bh >> 4, h = bh & 15;
#pragma unroll
  for (int pf = 0; pf < 4; ++pf) {
#pragma unroll
    for (int r = 0; r < 4; ++r) {
      const int col = kp32(h * PS + pf * 16 + c16);  // interleave for fc GEMM
      const int sA = qbase + g4 + r, sB = qbase + 16 + g4 + r;
      ctx[((size_t)(b * SS + sA)) * HS + col] = f2bf(o0[pf][r] * i0[r]);
      ctx[((size_t)(b * SS + sB)) * HS + col] = f2bf(o1[pf][r] * i1[r]);
    }
  }
}

extern "C" void kernel_launch(void* const* d_in, const int* in_sizes, int n_in,
                              void* d_out, int out_size, void* d_ws, size_t ws_size,
                              hipStream_t stream) {
  const float* q = (const float*)d_in[0];
  const float* k = (const float*)d_in[1];
  const float* v = (const float*)d_in[2];
  const float* ln_q_g = (const float*)d_in[3];
  const float* ln_q_b = (const float*)d_in[4];
  const float* ln_k_g = (const float*)d_in[5];
  const float* ln_k_b = (const float*)d_in[6];
  const float* ln_v_g = (const float*)d_in[7];
  const float* ln_v_b = (const float*)d_in[8];
  const float* w_q = (const float*)d_in[9];
  const float* w_k = (const float*)d_in[10];
  const float* w_v = (const float*)d_in[11];
  const float* w_fc = (const float*)d_in[12];
  const float* b_fc = (const float*)d_in[13];

  char* ws = (char*)d_ws;
  const bool merged = ws_size >= ((size_t)104 << 20);

  if (merged) {
    // xq/xk/xv [0,48M); weights [48M,56M); pq/pk/pv [56M,104M); ctx reuses xq
    unsigned short* xq = (unsigned short*)(ws);
    unsigned short* xk = (unsigned short*)(ws + (16 << 20));
    unsigned short* xv = (unsigned short*)(ws + (32 << 20));
    unsigned short* ctx = (unsigned short*)(ws);
    unsigned short* wqb = (unsigned short*)(ws + (48 << 20));
    unsigned short* wkb = (unsigned short*)(ws + (50 << 20));
    unsigned short* wvb = (unsigned short*)(ws + (52 << 20));
    unsigned short* wfcb = (unsigned short*)(ws + (54 << 20));
    unsigned short* pq = (unsigned short*)(ws + (56 << 20));
    unsigned short* pk = (unsigned short*)(ws + (72 << 20));
    unsigned short* pv = (unsigned short*)(ws + (88 << 20));

    castw_kernel<<<4096, 256, 0, stream>>>(w_q, w_k, w_v, w_fc, wqb, wkb, wvb, wfcb);
    ln3_kernel<<<dim3(MTOT, 3), 256, 0, stream>>>(q, k, v, ln_q_g, ln_q_b, ln_k_g,
                                                  ln_k_b, ln_v_g, ln_v_b, xq, xk, xv);
    gemm_qkv<<<dim3(8, 64, 3), 512, 0, stream>>>(xq, xk, xv, wqb, wkb, wvb, pq, pk, pv, 0);
    attn_kernel<<<dim3(8, 64), 512, 0, stream>>>(pq, pk, pv, ctx);
    gemm_fc<<<dim3(8, 64), 512, 0, stream>>>(ctx, wfcb, (float*)d_out, q, b_fc);
  } else {
    // sequential fallback: xln/ctx [0,16M); weights [16M,24M); proj [24M,72M)
    unsigned short* xln = (unsigned short*)(ws);
    unsigned short* ctx = (unsigned short*)(ws);
    unsigned short* wqb = (unsigned short*)(ws + (16 << 20));
    unsigned short* wkb = (unsigned short*)(ws + (18 << 20));
    unsigned short* wvb = (unsigned short*)(ws + (20 << 20));
    unsigned short* wfcb = (unsigned short*)(ws + (22 << 20));
    unsigned short* pq = (unsigned short*)(ws + (24 << 20));
    unsigned short* pk = (unsigned short*)(ws + (40 << 20));
    unsigned short* pv = (unsigned short*)(ws + (56 << 20));

    castw_kernel<<<4096, 256, 0, stream>>>(w_q, w_k, w_v, w_fc, wqb, wkb, wvb, wfcb);
    ln3_kernel<<<dim3(MTOT, 1), 256, 0, stream>>>(q, q, q, ln_q_g, ln_q_b, ln_q_g,
                                                  ln_q_b, ln_q_g, ln_q_b, xln, xln, xln);
    gemm_qkv<<<dim3(8, 64, 1), 512, 0, stream>>>(xln, xln, xln, wqb, wqb, wqb,
                                                 pq, pq, pq, 0);
    ln3_kernel<<<dim3(MTOT, 1), 256, 0, stream>>>(k, k, k, ln_k_g, ln_k_b, ln_k_g,
                                                  ln_k_b, ln_k_g, ln_k_b, xln, xln, xln);
    gemm_qkv<<<dim3(8, 64, 1), 512, 0, stream>>>(xln, xln, xln, wkb, wkb, wkb,
                                                 pk, pk, pk, 1);
    ln3_kernel<<<dim3(MTOT, 1), 256, 0, stream>>>(v, v, v, ln_v_g, ln_v_b, ln_v_g,
                                                  ln_v_b, ln_v_g, ln_v_b, xln, xln, xln);
    gemm_qkv<<<dim3(8, 64, 1), 512, 0, stream>>>(xln, xln, xln, wvb, wvb, wvb,
                                                 pv, pv, pv, 2);
    attn_kernel<<<dim3(8, 64), 512, 0, stream>>>(pq, pk, pv, ctx);
    gemm_fc<<<dim3(8, 64), 512, 0, stream>>>(ctx, wfcb, (float*)d_out, q, b_fc);
  }
}